// Round 3
// baseline (227.884 us; speedup 1.0000x reference)
//
#include <hip/hip_runtime.h>
#include <hip/hip_bf16.h>
#include <cstddef>

#define NH 16
#define HD 128
#define NW 4   // waves per block, splitting KV

using short4_t = __attribute__((ext_vector_type(4))) short;
using short8_t = __attribute__((ext_vector_type(8))) short;
using f32x4    = __attribute__((ext_vector_type(4))) float;

__device__ __forceinline__ short f2bf(float f) {
    union { float f; unsigned u; } x; x.f = f;
    unsigned r = x.u + 0x7FFFu + ((x.u >> 16) & 1u);
    return (short)(r >> 16);
}

// ---- pre-pass A: K [L][NH][HD] f32 -> Kb [NH][L][HD] bf16 ----
__global__ __launch_bounds__(256) void cvt_k_kernel(
    const float* __restrict__ K, short* __restrict__ Kb, int L)
{
    int idx = blockIdx.x * 256 + threadIdx.x;       // one per 8 elems
    int d8   = idx & (HD / 8 - 1);                  // 16 chunks per row
    int rest = idx >> 4;
    int h = rest & (NH - 1);
    int t = rest >> 4;
    const float* src = K + ((size_t)t * NH + h) * HD + d8 * 8;
    float4 a = ((const float4*)src)[0];
    float4 b = ((const float4*)src)[1];
    short8_t s;
    s[0] = f2bf(a.x); s[1] = f2bf(a.y); s[2] = f2bf(a.z); s[3] = f2bf(a.w);
    s[4] = f2bf(b.x); s[5] = f2bf(b.y); s[6] = f2bf(b.z); s[7] = f2bf(b.w);
    *(short8_t*)(Kb + ((size_t)h * L + t) * HD + d8 * 8) = s;
}

// ---- pre-pass B: V [L][NH][HD] f32 -> VTb [NH][HD][L] bf16 (transpose) ----
__global__ __launch_bounds__(256) void cvt_v_kernel(
    const float* __restrict__ V, short* __restrict__ VTb, int L)
{
    __shared__ short lds[HD][67];   // pad 67: 2-way max on write
    const int h  = blockIdx.y;
    const int t0 = blockIdx.x * 64;
    const int tid = threadIdx.x;
    #pragma unroll
    for (int p = 0; p < 8; ++p) {
        int r  = p * 8 + (tid >> 5);     // 0..63
        int c4 = tid & 31;               // float4 col
        float4 v = *(const float4*)(V + ((size_t)(t0 + r) * NH + h) * HD + c4 * 4);
        lds[c4 * 4 + 0][r] = f2bf(v.x);
        lds[c4 * 4 + 1][r] = f2bf(v.y);
        lds[c4 * 4 + 2][r] = f2bf(v.z);
        lds[c4 * 4 + 3][r] = f2bf(v.w);
    }
    __syncthreads();
    const int d  = tid >> 1;
    const int hf = tid & 1;
    short* dst = VTb + ((size_t)h * HD + d) * L + t0 + hf * 32;
    #pragma unroll
    for (int q = 0; q < 4; ++q) {
        short8_t w;
        #pragma unroll
        for (int j = 0; j < 8; ++j) w[j] = lds[d][hf * 32 + q * 8 + j];
        *(short8_t*)(dst + q * 8) = w;
    }
}

// ---- main kernel ----
// 4 waves per block, same 32 q-rows of one head; KV tiles strided across waves.
// Private online-softmax state per wave; flash-decode combine via LDS.
// Fragments (verified round 1/2):
//  S^T = mfma_16x16x32_bf16(A=K_tile, B=Q^T):  lane -> S[q=lane&15][kv=(lane>>4)*4+j]
//  O^T += mfma_16x16x16bf16_1k(A=V^T chunk, B=P^T): lane -> O[q=lane&15][d=c2*16+(lane>>4)*4+j]
template<bool PRE>
__global__ __launch_bounds__(256) void varlen_attn(
    const float* __restrict__ Q, const float* __restrict__ K,
    const float* __restrict__ V, const short* __restrict__ Kb,
    const short* __restrict__ VTb, const int* __restrict__ cu,
    int n_cu, int L, float* __restrict__ O)
{
    __shared__ float Osum[32][132];
    __shared__ float Mw[NW][32];
    __shared__ float Lw[NW][32];
    __shared__ float Linv[32];

    const int qt   = blockIdx.x;
    const int h    = blockIdx.y;
    const int tid  = threadIdx.x;
    const int w    = tid >> 6;
    const int lane = tid & 63;
    const int lo   = lane & 15;
    const int hi   = lane >> 4;

    int q_row[2];
    q_row[0] = qt * 32 + lo;
    q_row[1] = qt * 32 + 16 + lo;

    int seg_start[2];
    #pragma unroll
    for (int m = 0; m < 2; ++m) {
        int ss = 0;
        for (int i = 1; i < n_cu; ++i) { int c = cu[i]; if (c <= q_row[m]) ss = c; else break; }
        seg_start[m] = ss;
    }
    int ss0 = 0;
    { int q0 = qt * 32; for (int i = 1; i < n_cu; ++i) { int c = cu[i]; if (c <= q0) ss0 = c; else break; } }

    const float scale = 0.08838834764831845f; // 1/sqrt(128)

    short8_t qf[2][4];
    #pragma unroll
    for (int m = 0; m < 2; ++m) {
        const float* qp = Q + ((size_t)q_row[m] * NH + h) * HD + hi * 8;
        #pragma unroll
        for (int c = 0; c < 4; ++c) {
            float4 a = *(const float4*)(qp + c * 32);
            float4 b = *(const float4*)(qp + c * 32 + 4);
            short8_t s;
            s[0] = f2bf(a.x); s[1] = f2bf(a.y); s[2] = f2bf(a.z); s[3] = f2bf(a.w);
            s[4] = f2bf(b.x); s[5] = f2bf(b.y); s[6] = f2bf(b.z); s[7] = f2bf(b.w);
            qf[m][c] = s;
        }
    }

    f32x4 o[2][8];
    #pragma unroll
    for (int m = 0; m < 2; ++m)
        #pragma unroll
        for (int c = 0; c < 8; ++c) { o[m][c][0] = 0.f; o[m][c][1] = 0.f; o[m][c][2] = 0.f; o[m][c][3] = 0.f; }
    float mrow[2] = {-1e30f, -1e30f};
    float lrow[2] = {0.f, 0.f};

    const int kt0 = ss0 >> 4;
    const int kt1 = (qt * 32 + 31) >> 4;

    // fragment loaders
    auto loadK = [&](int kt, short8_t kf[4]) {
        if constexpr (PRE) {
            const short* kp = Kb + ((size_t)h * L + kt * 16 + lo) * HD + hi * 8;
            #pragma unroll
            for (int c = 0; c < 4; ++c) kf[c] = *(const short8_t*)(kp + c * 32);
        } else {
            const float* kp = K + ((size_t)(kt * 16 + lo) * NH + h) * HD + hi * 8;
            #pragma unroll
            for (int c = 0; c < 4; ++c) {
                float4 a = *(const float4*)(kp + c * 32);
                float4 b = *(const float4*)(kp + c * 32 + 4);
                short8_t s;
                s[0] = f2bf(a.x); s[1] = f2bf(a.y); s[2] = f2bf(a.z); s[3] = f2bf(a.w);
                s[4] = f2bf(b.x); s[5] = f2bf(b.y); s[6] = f2bf(b.z); s[7] = f2bf(b.w);
                kf[c] = s;
            }
        }
    };
    auto loadV = [&](int kt, short4_t vf[8]) {
        if constexpr (PRE) {
            const short* vp = VTb + ((size_t)h * HD + lo) * L + kt * 16 + hi * 4;
            #pragma unroll
            for (int c2 = 0; c2 < 8; ++c2)
                vf[c2] = *(const short4_t*)(vp + (size_t)c2 * 16 * L);
        } else {
            const float* vp = V + ((size_t)(kt * 16 + hi * 4) * NH + h) * HD + lo;
            #pragma unroll
            for (int c2 = 0; c2 < 8; ++c2) {
                short4_t s;
                #pragma unroll
                for (int j = 0; j < 4; ++j)
                    s[j] = f2bf(vp[(size_t)j * (NH * HD) + c2 * 16]);
                vf[c2] = s;
            }
        }
    };

    int kt = kt0 + w;
    short8_t kfc[4]; short4_t vfc[8];
    if (kt <= kt1) { loadK(kt, kfc); loadV(kt, vfc); }

    for (; kt <= kt1; kt += NW) {
        short8_t kfn[4]; short4_t vfn[8];
        const int ktn = kt + NW;
        if (ktn <= kt1) { loadK(ktn, kfn); loadV(ktn, vfn); }   // prefetch

        #pragma unroll
        for (int m = 0; m < 2; ++m) {
            f32x4 sacc; sacc[0] = 0.f; sacc[1] = 0.f; sacc[2] = 0.f; sacc[3] = 0.f;
            #pragma unroll
            for (int c = 0; c < 4; ++c)
                sacc = __builtin_amdgcn_mfma_f32_16x16x32_bf16(kfc[c], qf[m][c], sacc, 0, 0, 0);

            float tm = -1e30f;
            bool validj[4];
            #pragma unroll
            for (int j = 0; j < 4; ++j) {
                int kidx = kt * 16 + hi * 4 + j;
                validj[j] = (kidx >= seg_start[m]) && (kidx <= q_row[m]);
                float sc = sacc[j] * scale;
                sacc[j] = sc;
                if (validj[j]) tm = fmaxf(tm, sc);
            }
            tm = fmaxf(tm, __shfl_xor(tm, 16));
            tm = fmaxf(tm, __shfl_xor(tm, 32));

            // defer-rescale (T13): only rescale when the max actually grew
            if (!__all(tm <= mrow[m] + 8.0f)) {
                float mnew = fmaxf(mrow[m], tm);
                float sold = __expf(mrow[m] - mnew);
                lrow[m] *= sold;
                mrow[m] = mnew;
                #pragma unroll
                for (int c2 = 0; c2 < 8; ++c2) {
                    o[m][c2][0] *= sold; o[m][c2][1] *= sold;
                    o[m][c2][2] *= sold; o[m][c2][3] *= sold;
                }
            }

            float ps = 0.f;
            short4_t pf;
            #pragma unroll
            for (int j = 0; j < 4; ++j) {
                float pj = validj[j] ? __expf(sacc[j] - mrow[m]) : 0.f;
                ps += pj;
                pf[j] = f2bf(pj);
            }
            ps += __shfl_xor(ps, 16);
            ps += __shfl_xor(ps, 32);
            lrow[m] += ps;

            #pragma unroll
            for (int c2 = 0; c2 < 8; ++c2)
                o[m][c2] = __builtin_amdgcn_mfma_f32_16x16x16bf16_1k(vfc[c2], pf, o[m][c2], 0, 0, 0);
        }

        #pragma unroll
        for (int c = 0; c < 4; ++c) kfc[c] = kfn[c];
        #pragma unroll
        for (int c2 = 0; c2 < 8; ++c2) vfc[c2] = vfn[c2];
    }

    // ---- combine the NW partial (m,l,o) states ----
    if (hi == 0) {
        #pragma unroll
        for (int m = 0; m < 2; ++m) { Mw[w][m * 16 + lo] = mrow[m]; Lw[w][m * 16 + lo] = lrow[m]; }
    }
    __syncthreads();

    float sc2[2];
    #pragma unroll
    for (int m = 0; m < 2; ++m) {
        int r = m * 16 + lo;
        float M = Mw[0][r];
        #pragma unroll
        for (int ww = 1; ww < NW; ++ww) M = fmaxf(M, Mw[ww][r]);
        float Lt = 0.f;
        #pragma unroll
        for (int ww = 0; ww < NW; ++ww) Lt += Lw[ww][r] * __expf(Mw[ww][r] - M);
        sc2[m] = __expf(mrow[m] - M);
        if (w == 0 && hi == 0) Linv[r] = 1.0f / Lt;
    }

    #pragma unroll
    for (int t = 0; t < NW; ++t) {
        __syncthreads();
        if (w == t) {
            #pragma unroll
            for (int m = 0; m < 2; ++m) {
                #pragma unroll
                for (int c2 = 0; c2 < 8; ++c2) {
                    float4* dst = (float4*)&Osum[m * 16 + lo][c2 * 16 + hi * 4];
                    f32x4 v = o[m][c2];
                    float4 val;
                    val.x = v[0] * sc2[m]; val.y = v[1] * sc2[m];
                    val.z = v[2] * sc2[m]; val.w = v[3] * sc2[m];
                    if (t == 0) { *dst = val; }
                    else { float4 prev = *dst; prev.x += val.x; prev.y += val.y; prev.z += val.z; prev.w += val.w; *dst = prev; }
                }
            }
        }
    }
    __syncthreads();

    #pragma unroll
    for (int k = 0; k < 4; ++k) {
        int idx = k * 256 + tid;
        int r   = idx >> 5;
        int c4  = idx & 31;
        float4 v = *(const float4*)&Osum[r][c4 * 4];
        float li = Linv[r];
        v.x *= li; v.y *= li; v.z *= li; v.w *= li;
        *(float4*)(O + ((size_t)(qt * 32 + r) * NH + h) * HD + c4 * 4) = v;
    }
}

extern "C" void kernel_launch(void* const* d_in, const int* in_sizes, int n_in,
                              void* d_out, int out_size, void* d_ws, size_t ws_size,
                              hipStream_t stream) {
    const float* Q = (const float*)d_in[0];
    const float* K = (const float*)d_in[1];
    const float* V = (const float*)d_in[2];
    const int* cu  = (const int*)d_in[3];
    int n_cu = in_sizes[3];
    int L = in_sizes[0] / (NH * HD);

    const size_t elems = (size_t)NH * L * HD;
    const size_t need  = 2 * elems * sizeof(short);
    dim3 grid(L / 32, NH);

    if (ws_size >= need) {
        short* Kb  = (short*)d_ws;
        short* VTb = Kb + elems;
        cvt_k_kernel<<<(int)(elems / 8 / 256), 256, 0, stream>>>(K, Kb, L);
        cvt_v_kernel<<<dim3(L / 64, NH), 256, 0, stream>>>(V, VTb, L);
        varlen_attn<true><<<grid, 256, 0, stream>>>(Q, K, V, Kb, VTb, cu, n_cu, L, (float*)d_out);
    } else {
        varlen_attn<false><<<grid, 256, 0, stream>>>(Q, K, V, nullptr, nullptr, cu, n_cu, L, (float*)d_out);
    }
}

// Round 4
// 192.416 us; speedup vs baseline: 1.1843x; 1.1843x over previous
//
#include <hip/hip_runtime.h>
#include <hip/hip_bf16.h>
#include <cstddef>

#define NH 16
#define HD 128
#define NW 4                 // waves per block, splitting KV
#define PERSIST_BLOCKS 768   // 256 CU x 3 blocks/CU (VGPR-capped residency)

using short4_t = __attribute__((ext_vector_type(4))) short;
using short8_t = __attribute__((ext_vector_type(8))) short;
using f32x4    = __attribute__((ext_vector_type(4))) float;

__device__ __forceinline__ short f2bf(float f) {
    union { float f; unsigned u; } x; x.f = f;
    unsigned r = x.u + 0x7FFFu + ((x.u >> 16) & 1u);
    return (short)(r >> 16);
}

__global__ void zero_counter_kernel(unsigned* __restrict__ c) { *c = 0u; }

// ---- pre-pass A: K [L][NH][HD] f32 -> Kb [NH][L][HD] bf16 ----
__global__ __launch_bounds__(256) void cvt_k_kernel(
    const float* __restrict__ K, short* __restrict__ Kb, int L)
{
    int idx = blockIdx.x * 256 + threadIdx.x;       // one per 8 elems
    int d8   = idx & (HD / 8 - 1);
    int rest = idx >> 4;
    int h = rest & (NH - 1);
    int t = rest >> 4;
    const float* src = K + ((size_t)t * NH + h) * HD + d8 * 8;
    float4 a = ((const float4*)src)[0];
    float4 b = ((const float4*)src)[1];
    short8_t s;
    s[0] = f2bf(a.x); s[1] = f2bf(a.y); s[2] = f2bf(a.z); s[3] = f2bf(a.w);
    s[4] = f2bf(b.x); s[5] = f2bf(b.y); s[6] = f2bf(b.z); s[7] = f2bf(b.w);
    *(short8_t*)(Kb + ((size_t)h * L + t) * HD + d8 * 8) = s;
}

// ---- pre-pass B: V [L][NH][HD] f32 -> VTb [NH][HD][L] bf16 (transpose) ----
__global__ __launch_bounds__(256) void cvt_v_kernel(
    const float* __restrict__ V, short* __restrict__ VTb, int L)
{
    __shared__ short lds[HD][67];
    const int h  = blockIdx.y;
    const int t0 = blockIdx.x * 64;
    const int tid = threadIdx.x;
    #pragma unroll
    for (int p = 0; p < 8; ++p) {
        int r  = p * 8 + (tid >> 5);
        int c4 = tid & 31;
        float4 v = *(const float4*)(V + ((size_t)(t0 + r) * NH + h) * HD + c4 * 4);
        lds[c4 * 4 + 0][r] = f2bf(v.x);
        lds[c4 * 4 + 1][r] = f2bf(v.y);
        lds[c4 * 4 + 2][r] = f2bf(v.z);
        lds[c4 * 4 + 3][r] = f2bf(v.w);
    }
    __syncthreads();
    const int d  = tid >> 1;
    const int hf = tid & 1;
    short* dst = VTb + ((size_t)h * HD + d) * L + t0 + hf * 32;
    #pragma unroll
    for (int q = 0; q < 4; ++q) {
        short8_t w;
        #pragma unroll
        for (int j = 0; j < 8; ++j) w[j] = lds[d][hf * 32 + q * 8 + j];
        *(short8_t*)(dst + q * 8) = w;
    }
}

// ---- main kernel: persistent blocks, atomic queue, heavy-first ----
// Work unit = (qt, h): 32 q-rows of one head. 4 waves split the KV range
// (kt = kt0 + w + 4*i), private online-softmax state, flash-decode combine
// in LDS. Queue order h = unit&15, qt = nqt-1-(unit>>4) -> heaviest first.
// Fragments (verified rounds 1-3):
//  S^T = mfma_16x16x32_bf16(A=K_tile, B=Q^T):  lane -> S[q=lane&15][kv=(lane>>4)*4+j]
//  O^T += mfma_16x16x16bf16_1k(A=V^T chunk, B=P^T): lane -> O[q=lane&15][d=c2*16+(lane>>4)*4+j]
template<bool PRE>
__global__ __launch_bounds__(256) void varlen_attn(
    const float* __restrict__ Q, const float* __restrict__ K,
    const float* __restrict__ V, const short* __restrict__ Kb,
    const short* __restrict__ VTb, const int* __restrict__ cu,
    int n_cu, int L, int nqt, float* __restrict__ O,
    unsigned* __restrict__ counter)
{
    __shared__ float Osum[32][132];
    __shared__ float Mw[NW][32];
    __shared__ float Lw[NW][32];
    __shared__ float Linv[32];
    __shared__ unsigned s_unit;

    const int tid  = threadIdx.x;
    const int w    = tid >> 6;
    const int lane = tid & 63;
    const int lo   = lane & 15;
    const int hi   = lane >> 4;
    const unsigned nunits = (unsigned)(NH * nqt);
    const float scale = 0.08838834764831845f; // 1/sqrt(128)

    for (;;) {
        if (tid == 0) s_unit = counter ? atomicAdd(counter, 1u) : (unsigned)blockIdx.x;
        __syncthreads();
        const unsigned unit = s_unit;
        if (unit >= nunits) break;
        const int h  = unit & (NH - 1);
        const int qt = nqt - 1 - (int)(unit >> 4);   // heavy (big qt) first

        int q_row[2];
        q_row[0] = qt * 32 + lo;
        q_row[1] = qt * 32 + 16 + lo;

        int seg_start[2];
        #pragma unroll
        for (int m = 0; m < 2; ++m) {
            int ss = 0;
            for (int i = 1; i < n_cu; ++i) { int c = cu[i]; if (c <= q_row[m]) ss = c; else break; }
            seg_start[m] = ss;
        }
        int ss0 = 0;
        { int q0 = qt * 32; for (int i = 1; i < n_cu; ++i) { int c = cu[i]; if (c <= q0) ss0 = c; else break; } }

        // Q fragments with softmax scale folded in
        short8_t qf[2][4];
        #pragma unroll
        for (int m = 0; m < 2; ++m) {
            const float* qp = Q + ((size_t)q_row[m] * NH + h) * HD + hi * 8;
            #pragma unroll
            for (int c = 0; c < 4; ++c) {
                float4 a = *(const float4*)(qp + c * 32);
                float4 b = *(const float4*)(qp + c * 32 + 4);
                short8_t s;
                s[0] = f2bf(a.x * scale); s[1] = f2bf(a.y * scale);
                s[2] = f2bf(a.z * scale); s[3] = f2bf(a.w * scale);
                s[4] = f2bf(b.x * scale); s[5] = f2bf(b.y * scale);
                s[6] = f2bf(b.z * scale); s[7] = f2bf(b.w * scale);
                qf[m][c] = s;
            }
        }

        f32x4 o[2][8];
        #pragma unroll
        for (int m = 0; m < 2; ++m)
            #pragma unroll
            for (int c = 0; c < 8; ++c) { o[m][c][0] = 0.f; o[m][c][1] = 0.f; o[m][c][2] = 0.f; o[m][c][3] = 0.f; }
        float mrow[2] = {-1e30f, -1e30f};
        float lrow[2] = {0.f, 0.f};

        const int kt0 = ss0 >> 4;
        const int kt1 = (qt * 32 + 31) >> 4;

        auto loadK = [&](int kt, short8_t kf[4]) {
            if constexpr (PRE) {
                const short* kp = Kb + ((size_t)h * L + kt * 16 + lo) * HD + hi * 8;
                #pragma unroll
                for (int c = 0; c < 4; ++c) kf[c] = *(const short8_t*)(kp + c * 32);
            } else {
                const float* kp = K + ((size_t)(kt * 16 + lo) * NH + h) * HD + hi * 8;
                #pragma unroll
                for (int c = 0; c < 4; ++c) {
                    float4 a = *(const float4*)(kp + c * 32);
                    float4 b = *(const float4*)(kp + c * 32 + 4);
                    short8_t s;
                    s[0] = f2bf(a.x); s[1] = f2bf(a.y); s[2] = f2bf(a.z); s[3] = f2bf(a.w);
                    s[4] = f2bf(b.x); s[5] = f2bf(b.y); s[6] = f2bf(b.z); s[7] = f2bf(b.w);
                    kf[c] = s;
                }
            }
        };
        auto loadV = [&](int kt, short4_t vf[8]) {
            if constexpr (PRE) {
                const short* vp = VTb + ((size_t)h * HD + lo) * L + kt * 16 + hi * 4;
                #pragma unroll
                for (int c2 = 0; c2 < 8; ++c2)
                    vf[c2] = *(const short4_t*)(vp + (size_t)c2 * 16 * L);
            } else {
                const float* vp = V + ((size_t)(kt * 16 + hi * 4) * NH + h) * HD + lo;
                #pragma unroll
                for (int c2 = 0; c2 < 8; ++c2) {
                    short4_t s;
                    #pragma unroll
                    for (int j = 0; j < 4; ++j)
                        s[j] = f2bf(vp[(size_t)j * (NH * HD) + c2 * 16]);
                    vf[c2] = s;
                }
            }
        };

        int kt = kt0 + w;
        short8_t kfc[4]; short4_t vfc[8];
        if (kt <= kt1) { loadK(kt, kfc); loadV(kt, vfc); }

        for (; kt <= kt1; kt += NW) {
            short8_t kfn[4]; short4_t vfn[8];
            const int ktn = kt + NW;
            if (ktn <= kt1) { loadK(ktn, kfn); loadV(ktn, vfn); }   // prefetch

            #pragma unroll
            for (int m = 0; m < 2; ++m) {
                f32x4 sacc; sacc[0] = 0.f; sacc[1] = 0.f; sacc[2] = 0.f; sacc[3] = 0.f;
                #pragma unroll
                for (int c = 0; c < 4; ++c)
                    sacc = __builtin_amdgcn_mfma_f32_16x16x32_bf16(kfc[c], qf[m][c], sacc, 0, 0, 0);

                float tm = -1e30f;
                bool validj[4];
                #pragma unroll
                for (int j = 0; j < 4; ++j) {
                    int kidx = kt * 16 + hi * 4 + j;
                    validj[j] = (kidx >= seg_start[m]) && (kidx <= q_row[m]);
                    if (validj[j]) tm = fmaxf(tm, sacc[j]);
                }
                tm = fmaxf(tm, __shfl_xor(tm, 16));
                tm = fmaxf(tm, __shfl_xor(tm, 32));

                if (!__all(tm <= mrow[m] + 8.0f)) {   // defer-rescale (T13)
                    float mnew = fmaxf(mrow[m], tm);
                    float sold = __expf(mrow[m] - mnew);
                    lrow[m] *= sold;
                    mrow[m] = mnew;
                    #pragma unroll
                    for (int c2 = 0; c2 < 8; ++c2) {
                        o[m][c2][0] *= sold; o[m][c2][1] *= sold;
                        o[m][c2][2] *= sold; o[m][c2][3] *= sold;
                    }
                }

                float ps = 0.f;
                short4_t pf;
                #pragma unroll
                for (int j = 0; j < 4; ++j) {
                    float pj = validj[j] ? __expf(sacc[j] - mrow[m]) : 0.f;
                    ps += pj;
                    pf[j] = f2bf(pj);
                }
                ps += __shfl_xor(ps, 16);
                ps += __shfl_xor(ps, 32);
                lrow[m] += ps;

                #pragma unroll
                for (int c2 = 0; c2 < 8; ++c2)
                    o[m][c2] = __builtin_amdgcn_mfma_f32_16x16x16bf16_1k(vfc[c2], pf, o[m][c2], 0, 0, 0);
            }

            #pragma unroll
            for (int c = 0; c < 4; ++c) kfc[c] = kfn[c];
            #pragma unroll
            for (int c2 = 0; c2 < 8; ++c2) vfc[c2] = vfn[c2];
        }

        // ---- combine the NW partial (m,l,o) states ----
        if (hi == 0) {
            #pragma unroll
            for (int m = 0; m < 2; ++m) { Mw[w][m * 16 + lo] = mrow[m]; Lw[w][m * 16 + lo] = lrow[m]; }
        }
        __syncthreads();

        float sc2[2];
        #pragma unroll
        for (int m = 0; m < 2; ++m) {
            int r = m * 16 + lo;
            float M = Mw[0][r];
            #pragma unroll
            for (int ww = 1; ww < NW; ++ww) M = fmaxf(M, Mw[ww][r]);
            float Lt = 0.f;
            #pragma unroll
            for (int ww = 0; ww < NW; ++ww) Lt += Lw[ww][r] * __expf(Mw[ww][r] - M);
            sc2[m] = __expf(mrow[m] - M);
            if (w == 0 && hi == 0) Linv[r] = 1.0f / Lt;
        }

        #pragma unroll
        for (int t = 0; t < NW; ++t) {
            __syncthreads();
            if (w == t) {
                #pragma unroll
                for (int m = 0; m < 2; ++m) {
                    #pragma unroll
                    for (int c2 = 0; c2 < 8; ++c2) {
                        float4* dst = (float4*)&Osum[m * 16 + lo][c2 * 16 + hi * 4];
                        f32x4 v = o[m][c2];
                        float4 val;
                        val.x = v[0] * sc2[m]; val.y = v[1] * sc2[m];
                        val.z = v[2] * sc2[m]; val.w = v[3] * sc2[m];
                        if (t == 0) { *dst = val; }
                        else { float4 prev = *dst; prev.x += val.x; prev.y += val.y; prev.z += val.z; prev.w += val.w; *dst = prev; }
                    }
                }
            }
        }
        __syncthreads();

        #pragma unroll
        for (int k = 0; k < 4; ++k) {
            int idx = k * 256 + tid;
            int r   = idx >> 5;
            int c4  = idx & 31;
            float4 v = *(const float4*)&Osum[r][c4 * 4];
            float li = Linv[r];
            v.x *= li; v.y *= li; v.z *= li; v.w *= li;
            *(float4*)(O + ((size_t)(qt * 32 + r) * NH + h) * HD + c4 * 4) = v;
        }

        __syncthreads();          // protect s_unit / Osum before next unit
        if (!counter) break;      // static-grid fallback: one unit per block
    }
}

extern "C" void kernel_launch(void* const* d_in, const int* in_sizes, int n_in,
                              void* d_out, int out_size, void* d_ws, size_t ws_size,
                              hipStream_t stream) {
    const float* Q = (const float*)d_in[0];
    const float* K = (const float*)d_in[1];
    const float* V = (const float*)d_in[2];
    const int* cu  = (const int*)d_in[3];
    int n_cu = in_sizes[3];
    int L = in_sizes[0] / (NH * HD);
    int nqt = L / 32;

    const size_t elems = (size_t)NH * L * HD;
    const size_t need  = 256 + 2 * elems * sizeof(short);

    if (ws_size >= need) {
        unsigned* counter = (unsigned*)d_ws;
        short* Kb  = (short*)((char*)d_ws + 256);
        short* VTb = Kb + elems;
        zero_counter_kernel<<<1, 1, 0, stream>>>(counter);
        cvt_k_kernel<<<(int)(elems / 8 / 256), 256, 0, stream>>>(K, Kb, L);
        cvt_v_kernel<<<dim3(L / 64, NH), 256, 0, stream>>>(V, VTb, L);
        varlen_attn<true><<<PERSIST_BLOCKS, 256, 0, stream>>>(
            Q, K, V, Kb, VTb, cu, n_cu, L, nqt, (float*)d_out, counter);
    } else {
        varlen_attn<false><<<NH * nqt, 256, 0, stream>>>(
            Q, K, V, nullptr, nullptr, cu, n_cu, L, nqt, (float*)d_out, nullptr);
    }
}

// Round 5
// 175.225 us; speedup vs baseline: 1.3005x; 1.0981x over previous
//
#include <hip/hip_runtime.h>
#include <hip/hip_bf16.h>
#include <cstddef>

#define NH 16
#define HD 128
#define NW 4                 // waves per block, splitting KV
#define PERSIST_BLOCKS 768

using short4_t = __attribute__((ext_vector_type(4))) short;
using short8_t = __attribute__((ext_vector_type(8))) short;
using f32x4    = __attribute__((ext_vector_type(4))) float;

__device__ __forceinline__ short f2bf(float f) {
    union { float f; unsigned u; } x; x.f = f;
    unsigned r = x.u + 0x7FFFu + ((x.u >> 16) & 1u);
    return (short)(r >> 16);
}

__global__ void zero_counter_kernel(unsigned* __restrict__ c) { *c = 0u; }

// ---- pre-pass A: K [L][NH][HD] f32 -> Kf fragment-ordered bf16 ----
// Kf chunk (h, kt, c, lane) holds K[kt*16 + (lane&15)][c*32 + (lane>>4)*8 .. +7]
// so the hot loop loads kf[c] at base + lane*16B (fully coalesced).
__global__ __launch_bounds__(256) void cvt_k_kernel(
    const float* __restrict__ K, short* __restrict__ Kf, int L)
{
    int idx = blockIdx.x * 256 + threadIdx.x;   // one per 8 elems
    int d8   = idx & (HD / 8 - 1);              // 16 chunks per row
    int rest = idx >> 4;
    int h = rest & (NH - 1);
    int t = rest >> 4;
    const float* src = K + ((size_t)t * NH + h) * HD + d8 * 8;
    float4 a = ((const float4*)src)[0];
    float4 b = ((const float4*)src)[1];
    short8_t s;
    s[0] = f2bf(a.x); s[1] = f2bf(a.y); s[2] = f2bf(a.z); s[3] = f2bf(a.w);
    s[4] = f2bf(b.x); s[5] = f2bf(b.y); s[6] = f2bf(b.z); s[7] = f2bf(b.w);
    const int nkt = L >> 4;
    const int kt = t >> 4, lo = t & 15, c = d8 >> 2, hi = d8 & 3;
    size_t off = ((((size_t)h * nkt + kt) * 4 + c) * 64 + (hi * 16 + lo)) * 8;
    *(short8_t*)(Kf + off) = s;
}

// ---- pre-pass B: V [L][NH][HD] f32 -> Vf fragment-ordered bf16 ----
// Vf chunk (h, kt, cp, lane): elems j   = V[kt*16+(lane>>4)*4+j][(2cp  )*16+(lane&15)]
//                             elems j+4 = V[kt*16+(lane>>4)*4+j][(2cp+1)*16+(lane&15)]
__global__ __launch_bounds__(256) void cvt_v_kernel(
    const float* __restrict__ V, short* __restrict__ Vf, int L)
{
    __shared__ short lds[HD][67];
    const int h   = blockIdx.y;
    const int t0  = blockIdx.x * 64;   // 4 kt tiles per block
    const int tid = threadIdx.x;
    const int nkt = L >> 4;
    #pragma unroll
    for (int p = 0; p < 8; ++p) {
        int r  = p * 8 + (tid >> 5);
        int c4 = tid & 31;
        float4 v = *(const float4*)(V + ((size_t)(t0 + r) * NH + h) * HD + c4 * 4);
        lds[c4 * 4 + 0][r] = f2bf(v.x);
        lds[c4 * 4 + 1][r] = f2bf(v.y);
        lds[c4 * 4 + 2][r] = f2bf(v.z);
        lds[c4 * 4 + 3][r] = f2bf(v.w);
    }
    __syncthreads();
    #pragma unroll
    for (int it = 0; it < 4; ++it) {
        int out_id = it * 256 + tid;
        int lane = out_id & 63;
        int cp   = (out_id >> 6) & 3;
        int tt   = out_id >> 8;
        int lo = lane & 15, hi = lane >> 4;
        int tloc = tt * 16 + hi * 4;
        short8_t s;
        #pragma unroll
        for (int j = 0; j < 4; ++j) {
            s[j]     = lds[cp * 32 + lo][tloc + j];
            s[j + 4] = lds[cp * 32 + 16 + lo][tloc + j];
        }
        size_t off = ((((size_t)h * nkt + (t0 >> 4) + tt) * 4 + cp) * 64 + lane) * 8;
        *(short8_t*)(Vf + off) = s;
    }
}

// ---- main kernel: persistent blocks, atomic queue, heavy-first ----
// Work unit = (qt, h): 32 q-rows of one head; 4 waves split the KV tiles,
// private online-softmax state, flash-decode combine via LDS.
// Fragments (verified rounds 1-4):
//  S^T = mfma_16x16x32_bf16(A=K_tile, B=Q^T):  lane -> S[q=lane&15][kv=(lane>>4)*4+j]
//  O^T += mfma_16x16x16bf16_1k(A=V^T chunk, B=P^T): lane -> O[q=lane&15][d=c2*16+(lane>>4)*4+j]
template<bool PRE>
__global__ __launch_bounds__(256) void varlen_attn(
    const float* __restrict__ Q, const float* __restrict__ K,
    const float* __restrict__ V, const short* __restrict__ Kf,
    const short* __restrict__ Vf, const int* __restrict__ cu,
    int n_cu, int L, int nqt, float* __restrict__ O,
    unsigned* __restrict__ counter)
{
    __shared__ float Osum[32][132];
    __shared__ float Mw[NW][32];
    __shared__ float Lw[NW][32];
    __shared__ float Linv[32];
    __shared__ unsigned s_unit;

    const int tid  = threadIdx.x;
    const int w    = tid >> 6;
    const int lane = tid & 63;
    const int lo   = lane & 15;
    const int hi   = lane >> 4;
    const int nkt  = L >> 4;
    const unsigned nunits = (unsigned)(NH * nqt);
    const float scale = 0.08838834764831845f; // 1/sqrt(128)

    for (;;) {
        if (tid == 0) s_unit = counter ? atomicAdd(counter, 1u) : (unsigned)blockIdx.x;
        __syncthreads();
        const unsigned unit = s_unit;
        if (unit >= nunits) break;
        const int h  = unit & (NH - 1);
        const int qt = nqt - 1 - (int)(unit >> 4);   // heavy (big qt) first

        int q_row[2];
        q_row[0] = qt * 32 + lo;
        q_row[1] = qt * 32 + 16 + lo;

        int seg_start[2];
        #pragma unroll
        for (int m = 0; m < 2; ++m) {
            int ss = 0;
            for (int i = 1; i < n_cu; ++i) { int c = cu[i]; if (c <= q_row[m]) ss = c; else break; }
            seg_start[m] = ss;
        }
        int ss0 = 0;
        { int q0 = qt * 32; for (int i = 1; i < n_cu; ++i) { int c = cu[i]; if (c <= q0) ss0 = c; else break; } }

        // Q fragments with softmax scale folded in
        short8_t qf[2][4];
        #pragma unroll
        for (int m = 0; m < 2; ++m) {
            const float* qp = Q + ((size_t)q_row[m] * NH + h) * HD + hi * 8;
            #pragma unroll
            for (int c = 0; c < 4; ++c) {
                float4 a = *(const float4*)(qp + c * 32);
                float4 b = *(const float4*)(qp + c * 32 + 4);
                short8_t s;
                s[0] = f2bf(a.x * scale); s[1] = f2bf(a.y * scale);
                s[2] = f2bf(a.z * scale); s[3] = f2bf(a.w * scale);
                s[4] = f2bf(b.x * scale); s[5] = f2bf(b.y * scale);
                s[6] = f2bf(b.z * scale); s[7] = f2bf(b.w * scale);
                qf[m][c] = s;
            }
        }

        f32x4 o[2][8];
        #pragma unroll
        for (int m = 0; m < 2; ++m)
            #pragma unroll
            for (int c = 0; c < 8; ++c) { o[m][c][0] = 0.f; o[m][c][1] = 0.f; o[m][c][2] = 0.f; o[m][c][3] = 0.f; }
        float mrow[2] = {-1e30f, -1e30f};
        float lrow[2] = {0.f, 0.f};

        const int kt0 = ss0 >> 4;
        const int kt1 = (qt * 32 + 31) >> 4;

        // coalesced fragment loads (PRE): base + lane*16B
        auto loadK = [&](int kt, short8_t kf[4]) {
            if constexpr (PRE) {
                const short* kp = Kf + ((((size_t)h * nkt + kt) * 4) * 64 + lane) * 8;
                #pragma unroll
                for (int c = 0; c < 4; ++c) kf[c] = *(const short8_t*)(kp + (size_t)c * 512);
            } else {
                const float* kp = K + ((size_t)(kt * 16 + lo) * NH + h) * HD + hi * 8;
                #pragma unroll
                for (int c = 0; c < 4; ++c) {
                    float4 a = *(const float4*)(kp + c * 32);
                    float4 b = *(const float4*)(kp + c * 32 + 4);
                    short8_t s;
                    s[0] = f2bf(a.x); s[1] = f2bf(a.y); s[2] = f2bf(a.z); s[3] = f2bf(a.w);
                    s[4] = f2bf(b.x); s[5] = f2bf(b.y); s[6] = f2bf(b.z); s[7] = f2bf(b.w);
                    kf[c] = s;
                }
            }
        };
        auto loadV = [&](int kt, short8_t vw[4]) {
            if constexpr (PRE) {
                const short* vp = Vf + ((((size_t)h * nkt + kt) * 4) * 64 + lane) * 8;
                #pragma unroll
                for (int cp = 0; cp < 4; ++cp) vw[cp] = *(const short8_t*)(vp + (size_t)cp * 512);
            } else {
                const float* vp = V + ((size_t)(kt * 16 + hi * 4) * NH + h) * HD + lo;
                #pragma unroll
                for (int cp = 0; cp < 4; ++cp) {
                    short8_t s;
                    #pragma unroll
                    for (int j = 0; j < 4; ++j) {
                        s[j]     = f2bf(vp[(size_t)j * (NH * HD) + (2 * cp) * 16]);
                        s[j + 4] = f2bf(vp[(size_t)j * (NH * HD) + (2 * cp + 1) * 16]);
                    }
                    vw[cp] = s;
                }
            }
        };

        int kt = kt0 + w;
        short8_t kfc[4], vwc[4];
        if (kt <= kt1) { loadK(kt, kfc); loadV(kt, vwc); }

        for (; kt <= kt1; kt += NW) {
            short8_t kfn[4], vwn[4];
            const int ktn = kt + NW;
            if (ktn <= kt1) { loadK(ktn, kfn); loadV(ktn, vwn); }   // prefetch

            #pragma unroll
            for (int m = 0; m < 2; ++m) {
                f32x4 sacc; sacc[0] = 0.f; sacc[1] = 0.f; sacc[2] = 0.f; sacc[3] = 0.f;
                #pragma unroll
                for (int c = 0; c < 4; ++c)
                    sacc = __builtin_amdgcn_mfma_f32_16x16x32_bf16(kfc[c], qf[m][c], sacc, 0, 0, 0);

                float tm = -1e30f;
                bool validj[4];
                #pragma unroll
                for (int j = 0; j < 4; ++j) {
                    int kidx = kt * 16 + hi * 4 + j;
                    validj[j] = (kidx >= seg_start[m]) && (kidx <= q_row[m]);
                    if (validj[j]) tm = fmaxf(tm, sacc[j]);
                }
                tm = fmaxf(tm, __shfl_xor(tm, 16));
                tm = fmaxf(tm, __shfl_xor(tm, 32));

                if (!__all(tm <= mrow[m] + 8.0f)) {   // defer-rescale (T13)
                    float mnew = fmaxf(mrow[m], tm);
                    float sold = __expf(mrow[m] - mnew);
                    lrow[m] *= sold;
                    mrow[m] = mnew;
                    #pragma unroll
                    for (int c2 = 0; c2 < 8; ++c2) {
                        o[m][c2][0] *= sold; o[m][c2][1] *= sold;
                        o[m][c2][2] *= sold; o[m][c2][3] *= sold;
                    }
                }

                float ps = 0.f;
                short4_t pf;
                #pragma unroll
                for (int j = 0; j < 4; ++j) {
                    float pj = validj[j] ? __expf(sacc[j] - mrow[m]) : 0.f;
                    ps += pj;
                    pf[j] = f2bf(pj);
                }
                ps += __shfl_xor(ps, 16);
                ps += __shfl_xor(ps, 32);
                lrow[m] += ps;

                #pragma unroll
                for (int c2 = 0; c2 < 8; ++c2) {
                    short8_t wv = vwc[c2 >> 1];
                    short4_t vfrag;
                    if (c2 & 1) { vfrag[0] = wv[4]; vfrag[1] = wv[5]; vfrag[2] = wv[6]; vfrag[3] = wv[7]; }
                    else        { vfrag[0] = wv[0]; vfrag[1] = wv[1]; vfrag[2] = wv[2]; vfrag[3] = wv[3]; }
                    o[m][c2] = __builtin_amdgcn_mfma_f32_16x16x16bf16_1k(vfrag, pf, o[m][c2], 0, 0, 0);
                }
            }

            #pragma unroll
            for (int c = 0; c < 4; ++c) { kfc[c] = kfn[c]; vwc[c] = vwn[c]; }
        }

        // ---- combine the NW partial (m,l,o) states ----
        if (hi == 0) {
            #pragma unroll
            for (int m = 0; m < 2; ++m) { Mw[w][m * 16 + lo] = mrow[m]; Lw[w][m * 16 + lo] = lrow[m]; }
        }
        __syncthreads();

        float sc2[2];
        #pragma unroll
        for (int m = 0; m < 2; ++m) {
            int r = m * 16 + lo;
            float M = Mw[0][r];
            #pragma unroll
            for (int ww = 1; ww < NW; ++ww) M = fmaxf(M, Mw[ww][r]);
            float Lt = 0.f;
            #pragma unroll
            for (int ww = 0; ww < NW; ++ww) Lt += Lw[ww][r] * __expf(Mw[ww][r] - M);
            sc2[m] = __expf(mrow[m] - M);
            if (w == 0 && hi == 0) Linv[r] = 1.0f / Lt;
        }

        #pragma unroll
        for (int t = 0; t < NW; ++t) {
            __syncthreads();
            if (w == t) {
                #pragma unroll
                for (int m = 0; m < 2; ++m) {
                    #pragma unroll
                    for (int c2 = 0; c2 < 8; ++c2) {
                        float4* dst = (float4*)&Osum[m * 16 + lo][c2 * 16 + hi * 4];
                        f32x4 v = o[m][c2];
                        float4 val;
                        val.x = v[0] * sc2[m]; val.y = v[1] * sc2[m];
                        val.z = v[2] * sc2[m]; val.w = v[3] * sc2[m];
                        if (t == 0) { *dst = val; }
                        else { float4 prev = *dst; prev.x += val.x; prev.y += val.y; prev.z += val.z; prev.w += val.w; *dst = prev; }
                    }
                }
            }
        }
        __syncthreads();

        #pragma unroll
        for (int k = 0; k < 4; ++k) {
            int idx = k * 256 + tid;
            int r   = idx >> 5;
            int c4  = idx & 31;
            float4 v = *(const float4*)&Osum[r][c4 * 4];
            float li = Linv[r];
            v.x *= li; v.y *= li; v.z *= li; v.w *= li;
            *(float4*)(O + ((size_t)(qt * 32 + r) * NH + h) * HD + c4 * 4) = v;
        }

        __syncthreads();
        if (!counter) break;
    }
}

extern "C" void kernel_launch(void* const* d_in, const int* in_sizes, int n_in,
                              void* d_out, int out_size, void* d_ws, size_t ws_size,
                              hipStream_t stream) {
    const float* Q = (const float*)d_in[0];
    const float* K = (const float*)d_in[1];
    const float* V = (const float*)d_in[2];
    const int* cu  = (const int*)d_in[3];
    int n_cu = in_sizes[3];
    int L = in_sizes[0] / (NH * HD);
    int nqt = L / 32;

    const size_t elems = (size_t)NH * L * HD;
    const size_t need  = 256 + 2 * elems * sizeof(short);

    if (ws_size >= need) {
        unsigned* counter = (unsigned*)d_ws;
        short* Kf = (short*)((char*)d_ws + 256);
        short* Vf = Kf + elems;
        zero_counter_kernel<<<1, 1, 0, stream>>>(counter);
        cvt_k_kernel<<<(int)(elems / 8 / 256), 256, 0, stream>>>(K, Kf, L);
        cvt_v_kernel<<<dim3(L / 64, NH), 256, 0, stream>>>(V, Vf, L);
        varlen_attn<true><<<PERSIST_BLOCKS, 256, 0, stream>>>(
            Q, K, V, Kf, Vf, cu, n_cu, L, nqt, (float*)d_out, counter);
    } else {
        varlen_attn<false><<<NH * nqt, 256, 0, stream>>>(
            Q, K, V, nullptr, nullptr, cu, n_cu, L, nqt, (float*)d_out, nullptr);
    }
}

// Round 6
// 174.809 us; speedup vs baseline: 1.3036x; 1.0024x over previous
//
#include <hip/hip_runtime.h>
#include <hip/hip_bf16.h>
#include <cstddef>

#define NH 16
#define HD 128
#define NW 4                 // waves per block, splitting KV
#define PERSIST_BLOCKS 768

using short4_t = __attribute__((ext_vector_type(4))) short;
using short8_t = __attribute__((ext_vector_type(8))) short;
using f32x4    = __attribute__((ext_vector_type(4))) float;

__device__ __forceinline__ short f2bf(float f) {
    union { float f; unsigned u; } x; x.f = f;
    unsigned r = x.u + 0x7FFFu + ((x.u >> 16) & 1u);
    return (short)(r >> 16);
}

__global__ void zero_counter_kernel(unsigned* __restrict__ c) { *c = 0u; }

// ---- pre-pass A: K [L][NH][HD] f32 -> Kf fragment-ordered bf16 ----
// Kf chunk (h, kt, c, lane) holds K[kt*16 + (lane&15)][c*32 + (lane>>4)*8 .. +7]
// so the hot loop loads kf[c] at base + lane*16B (fully coalesced).
__global__ __launch_bounds__(256) void cvt_k_kernel(
    const float* __restrict__ K, short* __restrict__ Kf, int L)
{
    int idx = blockIdx.x * 256 + threadIdx.x;   // one per 8 elems
    int d8   = idx & (HD / 8 - 1);              // 16 chunks per row
    int rest = idx >> 4;
    int h = rest & (NH - 1);
    int t = rest >> 4;
    const float* src = K + ((size_t)t * NH + h) * HD + d8 * 8;
    float4 a = ((const float4*)src)[0];
    float4 b = ((const float4*)src)[1];
    short8_t s;
    s[0] = f2bf(a.x); s[1] = f2bf(a.y); s[2] = f2bf(a.z); s[3] = f2bf(a.w);
    s[4] = f2bf(b.x); s[5] = f2bf(b.y); s[6] = f2bf(b.z); s[7] = f2bf(b.w);
    const int nkt = L >> 4;
    const int kt = t >> 4, lo = t & 15, c = d8 >> 2, hi = d8 & 3;
    size_t off = ((((size_t)h * nkt + kt) * 4 + c) * 64 + (hi * 16 + lo)) * 8;
    *(short8_t*)(Kf + off) = s;
}

// ---- pre-pass B: V [L][NH][HD] f32 -> Vf fragment-ordered bf16 ----
// Vf chunk (h, kt, cp, lane): elems j   = V[kt*16+(lane>>4)*4+j][(2cp  )*16+(lane&15)]
//                             elems j+4 = V[kt*16+(lane>>4)*4+j][(2cp+1)*16+(lane&15)]
__global__ __launch_bounds__(256) void cvt_v_kernel(
    const float* __restrict__ V, short* __restrict__ Vf, int L)
{
    __shared__ short lds[HD][67];
    const int h   = blockIdx.y;
    const int t0  = blockIdx.x * 64;   // 4 kt tiles per block
    const int tid = threadIdx.x;
    const int nkt = L >> 4;
    #pragma unroll
    for (int p = 0; p < 8; ++p) {
        int r  = p * 8 + (tid >> 5);
        int c4 = tid & 31;
        float4 v = *(const float4*)(V + ((size_t)(t0 + r) * NH + h) * HD + c4 * 4);
        lds[c4 * 4 + 0][r] = f2bf(v.x);
        lds[c4 * 4 + 1][r] = f2bf(v.y);
        lds[c4 * 4 + 2][r] = f2bf(v.z);
        lds[c4 * 4 + 3][r] = f2bf(v.w);
    }
    __syncthreads();
    #pragma unroll
    for (int it = 0; it < 4; ++it) {
        int out_id = it * 256 + tid;
        int lane = out_id & 63;
        int cp   = (out_id >> 6) & 3;
        int tt   = out_id >> 8;
        int lo = lane & 15, hi = lane >> 4;
        int tloc = tt * 16 + hi * 4;
        short8_t s;
        #pragma unroll
        for (int j = 0; j < 4; ++j) {
            s[j]     = lds[cp * 32 + lo][tloc + j];
            s[j + 4] = lds[cp * 32 + 16 + lo][tloc + j];
        }
        size_t off = ((((size_t)h * nkt + (t0 >> 4) + tt) * 4 + cp) * 64 + lane) * 8;
        *(short8_t*)(Vf + off) = s;
    }
}

// ---- main kernel: persistent blocks, atomic queue, heavy-first ----
// Work unit = (qt, h): 32 q-rows of one head; 4 waves split the KV tiles,
// private online-softmax state, flash-decode combine via LDS.
// Fragments (verified rounds 1-4):
//  S^T = mfma_16x16x32_bf16(A=K_tile, B=Q^T):  lane -> S[q=lane&15][kv=(lane>>4)*4+j]
//  O^T += mfma_16x16x16bf16_1k(A=V^T chunk, B=P^T): lane -> O[q=lane&15][d=c2*16+(lane>>4)*4+j]
template<bool PRE>
__global__ __launch_bounds__(256) void varlen_attn(
    const float* __restrict__ Q, const float* __restrict__ K,
    const float* __restrict__ V, const short* __restrict__ Kf,
    const short* __restrict__ Vf, const int* __restrict__ cu,
    int n_cu, int L, int nqt, float* __restrict__ O,
    unsigned* __restrict__ counter)
{
    __shared__ float Osum[32][132];
    __shared__ float Mw[NW][32];
    __shared__ float Lw[NW][32];
    __shared__ float Linv[32];
    __shared__ unsigned s_unit;

    const int tid  = threadIdx.x;
    const int w    = tid >> 6;
    const int lane = tid & 63;
    const int lo   = lane & 15;
    const int hi   = lane >> 4;
    const int nkt  = L >> 4;
    const unsigned nunits = (unsigned)(NH * nqt);
    const float scale = 0.08838834764831845f; // 1/sqrt(128)

    for (;;) {
        if (tid == 0) s_unit = counter ? atomicAdd(counter, 1u) : (unsigned)blockIdx.x;
        __syncthreads();
        const unsigned unit = s_unit;
        if (unit >= nunits) break;
        const int h  = unit & (NH - 1);
        const int qt = nqt - 1 - (int)(unit >> 4);   // heavy (big qt) first

        int q_row[2];
        q_row[0] = qt * 32 + lo;
        q_row[1] = qt * 32 + 16 + lo;

        int seg_start[2];
        #pragma unroll
        for (int m = 0; m < 2; ++m) {
            int ss = 0;
            for (int i = 1; i < n_cu; ++i) { int c = cu[i]; if (c <= q_row[m]) ss = c; else break; }
            seg_start[m] = ss;
        }
        int ss0 = 0;
        { int q0 = qt * 32; for (int i = 1; i < n_cu; ++i) { int c = cu[i]; if (c <= q0) ss0 = c; else break; } }

        // Q fragments with softmax scale folded in
        short8_t qf[2][4];
        #pragma unroll
        for (int m = 0; m < 2; ++m) {
            const float* qp = Q + ((size_t)q_row[m] * NH + h) * HD + hi * 8;
            #pragma unroll
            for (int c = 0; c < 4; ++c) {
                float4 a = *(const float4*)(qp + c * 32);
                float4 b = *(const float4*)(qp + c * 32 + 4);
                short8_t s;
                s[0] = f2bf(a.x * scale); s[1] = f2bf(a.y * scale);
                s[2] = f2bf(a.z * scale); s[3] = f2bf(a.w * scale);
                s[4] = f2bf(b.x * scale); s[5] = f2bf(b.y * scale);
                s[6] = f2bf(b.z * scale); s[7] = f2bf(b.w * scale);
                qf[m][c] = s;
            }
        }

        f32x4 o[2][8];
        #pragma unroll
        for (int m = 0; m < 2; ++m)
            #pragma unroll
            for (int c = 0; c < 8; ++c) { o[m][c][0] = 0.f; o[m][c][1] = 0.f; o[m][c][2] = 0.f; o[m][c][3] = 0.f; }
        float mrow[2] = {-1e30f, -1e30f};
        float lrow[2] = {0.f, 0.f};

        const int kt0 = ss0 >> 4;
        const int kt1 = (qt * 32 + 31) >> 4;

        // coalesced fragment loads (PRE): base + lane*16B
        auto loadK = [&](int kt, short8_t kf[4]) {
            if constexpr (PRE) {
                const short* kp = Kf + ((((size_t)h * nkt + kt) * 4) * 64 + lane) * 8;
                #pragma unroll
                for (int c = 0; c < 4; ++c) kf[c] = *(const short8_t*)(kp + (size_t)c * 512);
            } else {
                const float* kp = K + ((size_t)(kt * 16 + lo) * NH + h) * HD + hi * 8;
                #pragma unroll
                for (int c = 0; c < 4; ++c) {
                    float4 a = *(const float4*)(kp + c * 32);
                    float4 b = *(const float4*)(kp + c * 32 + 4);
                    short8_t s;
                    s[0] = f2bf(a.x); s[1] = f2bf(a.y); s[2] = f2bf(a.z); s[3] = f2bf(a.w);
                    s[4] = f2bf(b.x); s[5] = f2bf(b.y); s[6] = f2bf(b.z); s[7] = f2bf(b.w);
                    kf[c] = s;
                }
            }
        };
        auto loadV = [&](int kt, short8_t vw[4]) {
            if constexpr (PRE) {
                const short* vp = Vf + ((((size_t)h * nkt + kt) * 4) * 64 + lane) * 8;
                #pragma unroll
                for (int cp = 0; cp < 4; ++cp) vw[cp] = *(const short8_t*)(vp + (size_t)cp * 512);
            } else {
                const float* vp = V + ((size_t)(kt * 16 + hi * 4) * NH + h) * HD + lo;
                #pragma unroll
                for (int cp = 0; cp < 4; ++cp) {
                    short8_t s;
                    #pragma unroll
                    for (int j = 0; j < 4; ++j) {
                        s[j]     = f2bf(vp[(size_t)j * (NH * HD) + (2 * cp) * 16]);
                        s[j + 4] = f2bf(vp[(size_t)j * (NH * HD) + (2 * cp + 1) * 16]);
                    }
                    vw[cp] = s;
                }
            }
        };

        int kt = kt0 + w;
        short8_t kfc[4], vwc[4];
        if (kt <= kt1) { loadK(kt, kfc); loadV(kt, vwc); }

        for (; kt <= kt1; kt += NW) {
            short8_t kfn[4], vwn[4];
            const int ktn = kt + NW;
            if (ktn <= kt1) { loadK(ktn, kfn); loadV(ktn, vwn); }   // prefetch

            #pragma unroll
            for (int m = 0; m < 2; ++m) {
                f32x4 sacc; sacc[0] = 0.f; sacc[1] = 0.f; sacc[2] = 0.f; sacc[3] = 0.f;
                #pragma unroll
                for (int c = 0; c < 4; ++c)
                    sacc = __builtin_amdgcn_mfma_f32_16x16x32_bf16(kfc[c], qf[m][c], sacc, 0, 0, 0);

                float tm = -1e30f;
                bool validj[4];
                #pragma unroll
                for (int j = 0; j < 4; ++j) {
                    int kidx = kt * 16 + hi * 4 + j;
                    validj[j] = (kidx >= seg_start[m]) && (kidx <= q_row[m]);
                    if (validj[j]) tm = fmaxf(tm, sacc[j]);
                }
                tm = fmaxf(tm, __shfl_xor(tm, 16));
                tm = fmaxf(tm, __shfl_xor(tm, 32));

                if (!__all(tm <= mrow[m] + 8.0f)) {   // defer-rescale (T13)
                    float mnew = fmaxf(mrow[m], tm);
                    float sold = __expf(mrow[m] - mnew);
                    lrow[m] *= sold;
                    mrow[m] = mnew;
                    #pragma unroll
                    for (int c2 = 0; c2 < 8; ++c2) {
                        o[m][c2][0] *= sold; o[m][c2][1] *= sold;
                        o[m][c2][2] *= sold; o[m][c2][3] *= sold;
                    }
                }

                float ps = 0.f;
                short4_t pf;
                #pragma unroll
                for (int j = 0; j < 4; ++j) {
                    float pj = validj[j] ? __expf(sacc[j] - mrow[m]) : 0.f;
                    ps += pj;
                    pf[j] = f2bf(pj);
                }
                ps += __shfl_xor(ps, 16);
                ps += __shfl_xor(ps, 32);
                lrow[m] += ps;

                #pragma unroll
                for (int c2 = 0; c2 < 8; ++c2) {
                    short8_t wv = vwc[c2 >> 1];
                    short4_t vfrag;
                    if (c2 & 1) { vfrag[0] = wv[4]; vfrag[1] = wv[5]; vfrag[2] = wv[6]; vfrag[3] = wv[7]; }
                    else        { vfrag[0] = wv[0]; vfrag[1] = wv[1]; vfrag[2] = wv[2]; vfrag[3] = wv[3]; }
                    o[m][c2] = __builtin_amdgcn_mfma_f32_16x16x16bf16_1k(vfrag, pf, o[m][c2], 0, 0, 0);
                }
            }

            #pragma unroll
            for (int c = 0; c < 4; ++c) { kfc[c] = kfn[c]; vwc[c] = vwn[c]; }
        }

        // ---- combine the NW partial (m,l,o) states ----
        if (hi == 0) {
            #pragma unroll
            for (int m = 0; m < 2; ++m) { Mw[w][m * 16 + lo] = mrow[m]; Lw[w][m * 16 + lo] = lrow[m]; }
        }
        __syncthreads();

        float sc2[2];
        #pragma unroll
        for (int m = 0; m < 2; ++m) {
            int r = m * 16 + lo;
            float M = Mw[0][r];
            #pragma unroll
            for (int ww = 1; ww < NW; ++ww) M = fmaxf(M, Mw[ww][r]);
            float Lt = 0.f;
            #pragma unroll
            for (int ww = 0; ww < NW; ++ww) Lt += Lw[ww][r] * __expf(Mw[ww][r] - M);
            sc2[m] = __expf(mrow[m] - M);
            if (w == 0 && hi == 0) Linv[r] = 1.0f / Lt;
        }

        #pragma unroll
        for (int t = 0; t < NW; ++t) {
            __syncthreads();
            if (w == t) {
                #pragma unroll
                for (int m = 0; m < 2; ++m) {
                    #pragma unroll
                    for (int c2 = 0; c2 < 8; ++c2) {
                        float4* dst = (float4*)&Osum[m * 16 + lo][c2 * 16 + hi * 4];
                        f32x4 v = o[m][c2];
                        float4 val;
                        val.x = v[0] * sc2[m]; val.y = v[1] * sc2[m];
                        val.z = v[2] * sc2[m]; val.w = v[3] * sc2[m];
                        if (t == 0) { *dst = val; }
                        else { float4 prev = *dst; prev.x += val.x; prev.y += val.y; prev.z += val.z; prev.w += val.w; *dst = prev; }
                    }
                }
            }
        }
        __syncthreads();

        #pragma unroll
        for (int k = 0; k < 4; ++k) {
            int idx = k * 256 + tid;
            int r   = idx >> 5;
            int c4  = idx & 31;
            float4 v = *(const float4*)&Osum[r][c4 * 4];
            float li = Linv[r];
            v.x *= li; v.y *= li; v.z *= li; v.w *= li;
            *(float4*)(O + ((size_t)(qt * 32 + r) * NH + h) * HD + c4 * 4) = v;
        }

        __syncthreads();
        if (!counter) break;
    }
}

extern "C" void kernel_launch(void* const* d_in, const int* in_sizes, int n_in,
                              void* d_out, int out_size, void* d_ws, size_t ws_size,
                              hipStream_t stream) {
    const float* Q = (const float*)d_in[0];
    const float* K = (const float*)d_in[1];
    const float* V = (const float*)d_in[2];
    const int* cu  = (const int*)d_in[3];
    int n_cu = in_sizes[3];
    int L = in_sizes[0] / (NH * HD);
    int nqt = L / 32;

    const size_t elems = (size_t)NH * L * HD;
    const size_t need  = 256 + 2 * elems * sizeof(short);

    if (ws_size >= need) {
        unsigned* counter = (unsigned*)d_ws;
        short* Kf = (short*)((char*)d_ws + 256);
        short* Vf = Kf + elems;
        zero_counter_kernel<<<1, 1, 0, stream>>>(counter);
        cvt_k_kernel<<<(int)(elems / 8 / 256), 256, 0, stream>>>(K, Kf, L);
        cvt_v_kernel<<<dim3(L / 64, NH), 256, 0, stream>>>(V, Vf, L);
        varlen_attn<true><<<PERSIST_BLOCKS, 256, 0, stream>>>(
            Q, K, V, Kf, Vf, cu, n_cu, L, nqt, (float*)d_out, counter);
    } else {
        varlen_attn<false><<<NH * nqt, 256, 0, stream>>>(
            Q, K, V, nullptr, nullptr, cu, n_cu, L, nqt, (float*)d_out, nullptr);
    }
}

// Round 7
// 128.413 us; speedup vs baseline: 1.7746x; 1.3613x over previous
//
#include <hip/hip_runtime.h>
#include <hip/hip_bf16.h>
#include <cstddef>

#define NH 16
#define HD 128
#define NW 4                 // waves per block, splitting KV
#define PERSIST_BLOCKS 768

using short4_t = __attribute__((ext_vector_type(4))) short;
using short8_t = __attribute__((ext_vector_type(8))) short;
using f32x4    = __attribute__((ext_vector_type(4))) float;

__device__ __forceinline__ short f2bf(float f) {
    union { float f; unsigned u; } x; x.f = f;
    unsigned r = x.u + 0x7FFFu + ((x.u >> 16) & 1u);
    return (short)(r >> 16);
}

__global__ void zero_counter_kernel(unsigned* __restrict__ c) { *c = 0u; }

// ---- pre-pass A: K [L][NH][HD] f32 -> Kf fragment-ordered bf16 ----
// Kf chunk (h, kt, c, lane) holds K[kt*16 + (lane&15)][c*32 + (lane>>4)*8 .. +7]
__global__ __launch_bounds__(256) void cvt_k_kernel(
    const float* __restrict__ K, short* __restrict__ Kf, int L)
{
    int idx = blockIdx.x * 256 + threadIdx.x;   // one per 8 elems
    int d8   = idx & (HD / 8 - 1);
    int rest = idx >> 4;
    int h = rest & (NH - 1);
    int t = rest >> 4;
    const float* src = K + ((size_t)t * NH + h) * HD + d8 * 8;
    float4 a = ((const float4*)src)[0];
    float4 b = ((const float4*)src)[1];
    short8_t s;
    s[0] = f2bf(a.x); s[1] = f2bf(a.y); s[2] = f2bf(a.z); s[3] = f2bf(a.w);
    s[4] = f2bf(b.x); s[5] = f2bf(b.y); s[6] = f2bf(b.z); s[7] = f2bf(b.w);
    const int nkt = L >> 4;
    const int kt = t >> 4, lo = t & 15, c = d8 >> 2, hi = d8 & 3;
    size_t off = ((((size_t)h * nkt + kt) * 4 + c) * 64 + (hi * 16 + lo)) * 8;
    *(short8_t*)(Kf + off) = s;
}

// ---- pre-pass B: V [L][NH][HD] f32 -> Vf fragment-ordered bf16 ----
// Vf chunk (h, kt, cp, lane): elems j   = V[kt*16+(lane>>4)*4+j][(2cp  )*16+(lane&15)]
//                             elems j+4 = V[kt*16+(lane>>4)*4+j][(2cp+1)*16+(lane&15)]
__global__ __launch_bounds__(256) void cvt_v_kernel(
    const float* __restrict__ V, short* __restrict__ Vf, int L)
{
    __shared__ short lds[HD][67];
    const int h   = blockIdx.y;
    const int t0  = blockIdx.x * 64;
    const int tid = threadIdx.x;
    const int nkt = L >> 4;
    #pragma unroll
    for (int p = 0; p < 8; ++p) {
        int r  = p * 8 + (tid >> 5);
        int c4 = tid & 31;
        float4 v = *(const float4*)(V + ((size_t)(t0 + r) * NH + h) * HD + c4 * 4);
        lds[c4 * 4 + 0][r] = f2bf(v.x);
        lds[c4 * 4 + 1][r] = f2bf(v.y);
        lds[c4 * 4 + 2][r] = f2bf(v.z);
        lds[c4 * 4 + 3][r] = f2bf(v.w);
    }
    __syncthreads();
    #pragma unroll
    for (int it = 0; it < 4; ++it) {
        int out_id = it * 256 + tid;
        int lane = out_id & 63;
        int cp   = (out_id >> 6) & 3;
        int tt   = out_id >> 8;
        int lo = lane & 15, hi = lane >> 4;
        int tloc = tt * 16 + hi * 4;
        short8_t s;
        #pragma unroll
        for (int j = 0; j < 4; ++j) {
            s[j]     = lds[cp * 32 + lo][tloc + j];
            s[j + 4] = lds[cp * 32 + 16 + lo][tloc + j];
        }
        size_t off = ((((size_t)h * nkt + (t0 >> 4) + tt) * 4 + cp) * 64 + lane) * 8;
        *(short8_t*)(Vf + off) = s;
    }
}

// ---- main kernel: persistent blocks, head-grouped heavy-first queue,
//      3-stage software pipeline (prefetch distance 2) ----
// Work unit = (qt, h). Queue order: h = unit / nqt (head-major => L2 locality:
// consecutive units share kt ranges of the same head); qt descending within
// head (heavy first). 4 waves split the KV tiles; flash-decode combine in LDS.
// Fragments (verified rounds 1-6):
//  S^T = mfma_16x16x32_bf16(A=K_tile, B=Q^T):  lane -> S[q=lane&15][kv=(lane>>4)*4+j]
//  O^T += mfma_16x16x16bf16_1k(A=V^T chunk, B=P^T): lane -> O[q=lane&15][d=c2*16+(lane>>4)*4+j]
template<bool PRE>
__global__ __launch_bounds__(256, 2) void varlen_attn(
    const float* __restrict__ Q, const float* __restrict__ K,
    const float* __restrict__ V, const short* __restrict__ Kf,
    const short* __restrict__ Vf, const int* __restrict__ cu,
    int n_cu, int L, int nqt, float* __restrict__ O,
    unsigned* __restrict__ counter)
{
    __shared__ float Osum[32][132];
    __shared__ float Mw[NW][32];
    __shared__ float Lw[NW][32];
    __shared__ float Linv[32];
    __shared__ unsigned s_unit;

    const int tid  = threadIdx.x;
    const int w    = tid >> 6;
    const int lane = tid & 63;
    const int lo   = lane & 15;
    const int hi   = lane >> 4;
    const int nkt  = L >> 4;
    const unsigned nunits = (unsigned)(NH * nqt);
    const float scale = 0.08838834764831845f; // 1/sqrt(128)

    for (;;) {
        if (tid == 0) s_unit = counter ? atomicAdd(counter, 1u) : (unsigned)blockIdx.x;
        __syncthreads();
        const unsigned unit = s_unit;
        if (unit >= nunits) break;
        const int h  = (int)(unit / (unsigned)nqt);          // head-major
        const int qt = nqt - 1 - (int)(unit % (unsigned)nqt); // heavy first

        int q_row[2];
        q_row[0] = qt * 32 + lo;
        q_row[1] = qt * 32 + 16 + lo;

        int seg_start[2];
        #pragma unroll
        for (int m = 0; m < 2; ++m) {
            int ss = 0;
            for (int i = 1; i < n_cu; ++i) { int c = cu[i]; if (c <= q_row[m]) ss = c; else break; }
            seg_start[m] = ss;
        }
        int ss0 = 0;
        { int q0 = qt * 32; for (int i = 1; i < n_cu; ++i) { int c = cu[i]; if (c <= q0) ss0 = c; else break; } }

        // Q fragments with softmax scale folded in
        short8_t qf[2][4];
        #pragma unroll
        for (int m = 0; m < 2; ++m) {
            const float* qp = Q + ((size_t)q_row[m] * NH + h) * HD + hi * 8;
            #pragma unroll
            for (int c = 0; c < 4; ++c) {
                float4 a = *(const float4*)(qp + c * 32);
                float4 b = *(const float4*)(qp + c * 32 + 4);
                short8_t s;
                s[0] = f2bf(a.x * scale); s[1] = f2bf(a.y * scale);
                s[2] = f2bf(a.z * scale); s[3] = f2bf(a.w * scale);
                s[4] = f2bf(b.x * scale); s[5] = f2bf(b.y * scale);
                s[6] = f2bf(b.z * scale); s[7] = f2bf(b.w * scale);
                qf[m][c] = s;
            }
        }

        f32x4 o[2][8];
        #pragma unroll
        for (int m = 0; m < 2; ++m)
            #pragma unroll
            for (int c = 0; c < 8; ++c) { o[m][c][0] = 0.f; o[m][c][1] = 0.f; o[m][c][2] = 0.f; o[m][c][3] = 0.f; }
        float mrow[2] = {-1e30f, -1e30f};
        float lrow[2] = {0.f, 0.f};

        const int kt0 = ss0 >> 4;
        const int kt1 = (qt * 32 + 31) >> 4;

        auto loadK = [&](int kt, short8_t (&kf)[4]) {
            if constexpr (PRE) {
                const short* kp = Kf + ((((size_t)h * nkt + kt) * 4) * 64 + lane) * 8;
                #pragma unroll
                for (int c = 0; c < 4; ++c) kf[c] = *(const short8_t*)(kp + (size_t)c * 512);
            } else {
                const float* kp = K + ((size_t)(kt * 16 + lo) * NH + h) * HD + hi * 8;
                #pragma unroll
                for (int c = 0; c < 4; ++c) {
                    float4 a = *(const float4*)(kp + c * 32);
                    float4 b = *(const float4*)(kp + c * 32 + 4);
                    short8_t s;
                    s[0] = f2bf(a.x); s[1] = f2bf(a.y); s[2] = f2bf(a.z); s[3] = f2bf(a.w);
                    s[4] = f2bf(b.x); s[5] = f2bf(b.y); s[6] = f2bf(b.z); s[7] = f2bf(b.w);
                    kf[c] = s;
                }
            }
        };
        auto loadV = [&](int kt, short8_t (&vw)[4]) {
            if constexpr (PRE) {
                const short* vp = Vf + ((((size_t)h * nkt + kt) * 4) * 64 + lane) * 8;
                #pragma unroll
                for (int cp = 0; cp < 4; ++cp) vw[cp] = *(const short8_t*)(vp + (size_t)cp * 512);
            } else {
                const float* vp = V + ((size_t)(kt * 16 + hi * 4) * NH + h) * HD + lo;
                #pragma unroll
                for (int cp = 0; cp < 4; ++cp) {
                    short8_t s;
                    #pragma unroll
                    for (int j = 0; j < 4; ++j) {
                        s[j]     = f2bf(vp[(size_t)j * (NH * HD) + (2 * cp) * 16]);
                        s[j + 4] = f2bf(vp[(size_t)j * (NH * HD) + (2 * cp + 1) * 16]);
                    }
                    vw[cp] = s;
                }
            }
        };

        auto compute = [&](short8_t (&kf)[4], short8_t (&vw)[4], int kt) {
            #pragma unroll
            for (int m = 0; m < 2; ++m) {
                f32x4 sacc; sacc[0] = 0.f; sacc[1] = 0.f; sacc[2] = 0.f; sacc[3] = 0.f;
                __builtin_amdgcn_s_setprio(1);
                #pragma unroll
                for (int c = 0; c < 4; ++c)
                    sacc = __builtin_amdgcn_mfma_f32_16x16x32_bf16(kf[c], qf[m][c], sacc, 0, 0, 0);
                __builtin_amdgcn_s_setprio(0);

                float tm = -1e30f;
                bool validj[4];
                #pragma unroll
                for (int j = 0; j < 4; ++j) {
                    int kidx = kt * 16 + hi * 4 + j;
                    validj[j] = (kidx >= seg_start[m]) && (kidx <= q_row[m]);
                    if (validj[j]) tm = fmaxf(tm, sacc[j]);
                }
                tm = fmaxf(tm, __shfl_xor(tm, 16));
                tm = fmaxf(tm, __shfl_xor(tm, 32));

                if (!__all(tm <= mrow[m] + 8.0f)) {   // defer-rescale (T13)
                    float mnew = fmaxf(mrow[m], tm);
                    float sold = __expf(mrow[m] - mnew);
                    lrow[m] *= sold;
                    mrow[m] = mnew;
                    #pragma unroll
                    for (int c2 = 0; c2 < 8; ++c2) {
                        o[m][c2][0] *= sold; o[m][c2][1] *= sold;
                        o[m][c2][2] *= sold; o[m][c2][3] *= sold;
                    }
                }

                float ps = 0.f;
                short4_t pf;
                #pragma unroll
                for (int j = 0; j < 4; ++j) {
                    float pj = validj[j] ? __expf(sacc[j] - mrow[m]) : 0.f;
                    ps += pj;
                    pf[j] = f2bf(pj);
                }
                ps += __shfl_xor(ps, 16);
                ps += __shfl_xor(ps, 32);
                lrow[m] += ps;

                __builtin_amdgcn_s_setprio(1);
                #pragma unroll
                for (int c2 = 0; c2 < 8; ++c2) {
                    short8_t wv = vw[c2 >> 1];
                    short4_t vfrag;
                    if (c2 & 1) { vfrag[0] = wv[4]; vfrag[1] = wv[5]; vfrag[2] = wv[6]; vfrag[3] = wv[7]; }
                    else        { vfrag[0] = wv[0]; vfrag[1] = wv[1]; vfrag[2] = wv[2]; vfrag[3] = wv[3]; }
                    o[m][c2] = __builtin_amdgcn_mfma_f32_16x16x16bf16_1k(vfrag, pf, o[m][c2], 0, 0, 0);
                }
                __builtin_amdgcn_s_setprio(0);
            }
        };

        // ---- 3-stage pipeline, prefetch distance 2, clamped tail loads ----
        {
            const int ktA = kt0 + w;
            if (ktA <= kt1) {
                short8_t k0[4], v0[4], k1[4], v1[4], k2[4], v2[4];
                loadK(ktA, k0); loadV(ktA, v0);
                {
                    int p = ktA + NW; if (p > kt1) p = kt1;
                    loadK(p, k1); loadV(p, v1);
                }
                for (int kt = ktA; kt <= kt1; kt += 3 * NW) {
                    { int p = kt + 2 * NW; if (p > kt1) p = kt1; loadK(p, k2); loadV(p, v2); }
                    compute(k0, v0, kt);
                    if (kt + NW <= kt1) {
                        { int p = kt + 3 * NW; if (p > kt1) p = kt1; loadK(p, k0); loadV(p, v0); }
                        compute(k1, v1, kt + NW);
                        if (kt + 2 * NW <= kt1) {
                            { int p = kt + 4 * NW; if (p > kt1) p = kt1; loadK(p, k1); loadV(p, v1); }
                            compute(k2, v2, kt + 2 * NW);
                        }
                    }
                }
            }
        }

        // ---- combine the NW partial (m,l,o) states ----
        if (hi == 0) {
            #pragma unroll
            for (int m = 0; m < 2; ++m) { Mw[w][m * 16 + lo] = mrow[m]; Lw[w][m * 16 + lo] = lrow[m]; }
        }
        __syncthreads();

        float sc2[2];
        #pragma unroll
        for (int m = 0; m < 2; ++m) {
            int r = m * 16 + lo;
            float M = Mw[0][r];
            #pragma unroll
            for (int ww = 1; ww < NW; ++ww) M = fmaxf(M, Mw[ww][r]);
            float Lt = 0.f;
            #pragma unroll
            for (int ww = 0; ww < NW; ++ww) Lt += Lw[ww][r] * __expf(Mw[ww][r] - M);
            sc2[m] = __expf(mrow[m] - M);
            if (w == 0 && hi == 0) Linv[r] = 1.0f / Lt;
        }

        #pragma unroll
        for (int t = 0; t < NW; ++t) {
            __syncthreads();
            if (w == t) {
                #pragma unroll
                for (int m = 0; m < 2; ++m) {
                    #pragma unroll
                    for (int c2 = 0; c2 < 8; ++c2) {
                        float4* dst = (float4*)&Osum[m * 16 + lo][c2 * 16 + hi * 4];
                        f32x4 v = o[m][c2];
                        float4 val;
                        val.x = v[0] * sc2[m]; val.y = v[1] * sc2[m];
                        val.z = v[2] * sc2[m]; val.w = v[3] * sc2[m];
                        if (t == 0) { *dst = val; }
                        else { float4 prev = *dst; prev.x += val.x; prev.y += val.y; prev.z += val.z; prev.w += val.w; *dst = prev; }
                    }
                }
            }
        }
        __syncthreads();

        #pragma unroll
        for (int k = 0; k < 4; ++k) {
            int idx = k * 256 + tid;
            int r   = idx >> 5;
            int c4  = idx & 31;
            float4 v = *(const float4*)&Osum[r][c4 * 4];
            float li = Linv[r];
            v.x *= li; v.y *= li; v.z *= li; v.w *= li;
            *(float4*)(O + ((size_t)(qt * 32 + r) * NH + h) * HD + c4 * 4) = v;
        }

        __syncthreads();
        if (!counter) break;
    }
}

extern "C" void kernel_launch(void* const* d_in, const int* in_sizes, int n_in,
                              void* d_out, int out_size, void* d_ws, size_t ws_size,
                              hipStream_t stream) {
    const float* Q = (const float*)d_in[0];
    const float* K = (const float*)d_in[1];
    const float* V = (const float*)d_in[2];
    const int* cu  = (const int*)d_in[3];
    int n_cu = in_sizes[3];
    int L = in_sizes[0] / (NH * HD);
    int nqt = L / 32;

    const size_t elems = (size_t)NH * L * HD;
    const size_t need  = 256 + 2 * elems * sizeof(short);

    if (ws_size >= need) {
        unsigned* counter = (unsigned*)d_ws;
        short* Kf = (short*)((char*)d_ws + 256);
        short* Vf = Kf + elems;
        zero_counter_kernel<<<1, 1, 0, stream>>>(counter);
        cvt_k_kernel<<<(int)(elems / 8 / 256), 256, 0, stream>>>(K, Kf, L);
        cvt_v_kernel<<<dim3(L / 64, NH), 256, 0, stream>>>(V, Vf, L);
        varlen_attn<true><<<PERSIST_BLOCKS, 256, 0, stream>>>(
            Q, K, V, Kf, Vf, cu, n_cu, L, nqt, (float*)d_out, counter);
    } else {
        varlen_attn<false><<<NH * nqt, 256, 0, stream>>>(
            Q, K, V, nullptr, nullptr, cu, n_cu, L, nqt, (float*)d_out, nullptr);
    }
}